// Round 1
// 749.551 us; speedup vs baseline: 1.0131x; 1.0131x over previous
//
#include <hip/hip_runtime.h>

#define N_CELLS 8388608
#define N_HALO  1048576

// Direct q-phased gather: no workspace, no packed copy.
//
// derived row -> fields rows:
//   0:u(0) 1:v(1) 2:b_u(2) 3:b_v(3) 4:h(4) 5:hh(6) 6:dif_h(7)
//   7:h+Hb(4,5) 8:eta1(8) 9:min(k_u,k3)(9,11) 10:min(k_v,k3)(10,11)
//
// 5 phases, 4096 blocks each (1 halo element / thread). Each phase touches
// <=3 field rows (96 MB) + src_idx/weights (16 MB) -> Infinity-Cache
// resident, so the random 4-B gathers are served by L3/L2, not HBM.
// Blocks are dispatched in linear order, so phases run ~sequentially;
// at most 2 phases are co-resident (<=160 MB working set < 256 MB L3).
__global__ __launch_bounds__(256) void halo_gather(
    const float* __restrict__ fields, const int2* __restrict__ src_idx,
    const float2* __restrict__ weights, float* __restrict__ out)
{
    const int bid   = blockIdx.x;
    const int phase = bid >> 12;                  // 4096 blocks per phase
    const int e     = ((bid & 4095) << 8) | threadIdx.x;

    const int2   ij  = src_idx[e];
    const float2 wv  = weights[e];
    const float  w0  = wv.x, w1 = wv.y;
    const bool   two = (w1 != 0.0f);              // ~50% of elements: 1 source
    const size_t ix  = (size_t)ij.x, iy = (size_t)ij.y;

    switch (phase) {
    case 0: {  // rows {u,v} -> out {0,1}
        const float* r0 = fields + 0ull * N_CELLS;
        const float* r1 = fields + 1ull * N_CELLS;
        float o0 = r0[ix] * w0, o1 = r1[ix] * w0;
        if (two) { o0 += r0[iy] * w1; o1 += r1[iy] * w1; }
        __builtin_nontemporal_store(o0, out + 0ull * N_HALO + e);
        __builtin_nontemporal_store(o1, out + 1ull * N_HALO + e);
        break; }
    case 1: {  // rows {b_u,b_v} -> out {2,3}
        const float* r2 = fields + 2ull * N_CELLS;
        const float* r3 = fields + 3ull * N_CELLS;
        float o2 = r2[ix] * w0, o3 = r3[ix] * w0;
        if (two) { o2 += r2[iy] * w1; o3 += r3[iy] * w1; }
        __builtin_nontemporal_store(o2, out + 2ull * N_HALO + e);
        __builtin_nontemporal_store(o3, out + 3ull * N_HALO + e);
        break; }
    case 2: {  // rows {h,Hb} -> out {4: h, 7: h+Hb}
        const float* r4 = fields + 4ull * N_CELLS;
        const float* r5 = fields + 5ull * N_CELLS;
        float ha = r4[ix], hba = r5[ix];
        float o4 = ha * w0, o7 = (ha + hba) * w0;
        if (two) {
            float hb = r4[iy], hbb = r5[iy];
            o4 += hb * w1; o7 += (hb + hbb) * w1;
        }
        __builtin_nontemporal_store(o4, out + 4ull * N_HALO + e);
        __builtin_nontemporal_store(o7, out + 7ull * N_HALO + e);
        break; }
    case 3: {  // rows {hh,dif_h,eta1} -> out {5,6,8}
        const float* r6 = fields + 6ull * N_CELLS;
        const float* r7 = fields + 7ull * N_CELLS;
        const float* r8 = fields + 8ull * N_CELLS;
        float o5 = r6[ix] * w0, o6 = r7[ix] * w0, o8 = r8[ix] * w0;
        if (two) { o5 += r6[iy] * w1; o6 += r7[iy] * w1; o8 += r8[iy] * w1; }
        __builtin_nontemporal_store(o5, out + 5ull * N_HALO + e);
        __builtin_nontemporal_store(o6, out + 6ull * N_HALO + e);
        __builtin_nontemporal_store(o8, out + 8ull * N_HALO + e);
        break; }
    default: {  // rows {k_u,k_v,k3} -> out {9: min(k_u,k3), 10: min(k_v,k3)}
        const float* r9  = fields +  9ull * N_CELLS;
        const float* r10 = fields + 10ull * N_CELLS;
        const float* r11 = fields + 11ull * N_CELLS;
        float kua = r9[ix], kva = r10[ix], k3a = r11[ix];
        float o9  = fminf(kua, k3a) * w0;
        float o10 = fminf(kva, k3a) * w0;
        if (two) {
            float kub = r9[iy], kvb = r10[iy], k3b = r11[iy];
            o9  += fminf(kub, k3b) * w1;
            o10 += fminf(kvb, k3b) * w1;
        }
        __builtin_nontemporal_store(o9,  out +  9ull * N_HALO + e);
        __builtin_nontemporal_store(o10, out + 10ull * N_HALO + e);
        break; }
    }
}

extern "C" void kernel_launch(void* const* d_in, const int* in_sizes, int n_in,
                              void* d_out, int out_size, void* d_ws, size_t ws_size,
                              hipStream_t stream) {
    const float*  fields  = (const float*)d_in[0];
    const int2*   src_idx = (const int2*)d_in[1];
    const float2* weights = (const float2*)d_in[2];
    float* out = (float*)d_out;
    (void)d_ws; (void)ws_size;  // no workspace: the packed copy is gone

    halo_gather<<<5 * (N_HALO / 256), 256, 0, stream>>>(fields, src_idx, weights, out);
}